// Round 4
// baseline (731.446 us; speedup 1.0000x reference)
//
#include <hip/hip_runtime.h>
#include <hip/hip_bf16.h>
#include <math.h>

#define N_NODES 100000
#define N_EDGES 1200000
#define NT_EDGE 75000          // total 16-edge tiles
#define NPASS   3
#define TILES_PER_PASS 25000   // NT_EDGE / NPASS
#define ROWS_PER_PASS  400000  // TILES_PER_PASS * 16
#define NT_POST 6250           // node tiles of 16
#define AVG_D   2.5649493574615367f
#define EPSV    1e-5f

typedef __attribute__((ext_vector_type(8))) short short8;
typedef __attribute__((ext_vector_type(4))) float f32x4;

struct ERec { unsigned eid, sn, dn; };   // 12 B packed CSR record

// ---- workspace layout (bytes), total 132,005,120 (< 135,205,120 proven) ----
#define OFF_DEG       0u
#define OFF_ROWLOCAL  400000u
#define OFF_BSUM      800000u         // 2048; dead after scans -> reused as CARRY
#define OFF_BOFFS     802048u
#define OFF_ROWSTART  804096u
#define OFF_CURSOR    1204096u
#define OFF_EREC      1604096u        // E * 12 B = 14.4 MB
#define OFF_AB        16004096u       // N*2 f32
#define OFF_BNACC     16804096u       // 128 f32
#define OFF_BNFIN     16804608u       // 128 f32
#define OFF_HB        16805120u       // N*64 bf16 = 12.8 MB
#define OFF_MBUF      29605120u       // 400000 rows * 64 bf16 = 51.2 MB
#define OFF_AGG       80805120u       // N*256 bf16 = 51.2 MB  (end 132,005,120)
#define OFF_CARRY     OFF_BSUM        // 2 splits * 4 stats * 64 f32 = 2048 B
#define OFF_OUTPRE    OFF_MBUF        // N*64 f32 = 25.6 MB, mbuf dead by k_post

__device__ __forceinline__ short f2b(float f){          // fp32 -> bf16 bits (RNE)
    union { float f; unsigned u; } c; c.f = f;
    unsigned u = c.u;
    unsigned r = (u + 0x7fffu + ((u >> 16) & 1u)) >> 16;
    return (short)r;
}
__device__ __forceinline__ float b2f(unsigned u16){     // bf16 bits (low 16) -> fp32
    union { unsigned u; float f; } c; c.u = u16 << 16;
    return c.f;
}
__device__ __forceinline__ unsigned pk(float a, float b){
    return ((unsigned)(unsigned short)f2b(a)) | (((unsigned)(unsigned short)f2b(b)) << 16);
}

// ================= CSR build + h->bf16 conversion =================
__global__ void k_prep(const int* __restrict__ dst, unsigned* __restrict__ deg,
                       const float* __restrict__ h, unsigned short* __restrict__ hb){
    int i = blockIdx.x*256 + threadIdx.x;
    if (i < N_EDGES) atomicAdd(&deg[dst[i]], 1u);
    if (i < 800000){                                    // 8 floats per thread
        const float4* p = (const float4*)h + (size_t)i*2;
        float4 u0 = p[0], u1 = p[1];
        uint4 o;
        o.x = pk(u0.x,u0.y); o.y = pk(u0.z,u0.w);
        o.z = pk(u1.x,u1.y); o.w = pk(u1.z,u1.w);
        ((uint4*)hb)[i] = o;
    }
}
__global__ void k_scan1(const unsigned* __restrict__ deg, unsigned* __restrict__ rowlocal,
                        unsigned* __restrict__ bsum){
    __shared__ unsigned s[256];
    int t = threadIdx.x; int i = blockIdx.x*256 + t;
    unsigned d = (i < N_NODES) ? deg[i] : 0u;
    s[t] = d; __syncthreads();
    for (int off=1; off<256; off<<=1){
        unsigned v = (t>=off) ? s[t-off] : 0u; __syncthreads();
        s[t] += v; __syncthreads();
    }
    if (i < N_NODES) rowlocal[i] = s[t] - d;
    if (t == 255) bsum[blockIdx.x] = s[255];
}
__global__ void k_scan2(const unsigned* __restrict__ bsum, unsigned* __restrict__ boffs){
    __shared__ unsigned s[512];
    int t = threadIdx.x;
    unsigned v = (t < 391) ? bsum[t] : 0u;
    s[t] = v; __syncthreads();
    for (int off=1; off<512; off<<=1){
        unsigned x = (t>=off) ? s[t-off] : 0u; __syncthreads();
        s[t] += x; __syncthreads();
    }
    boffs[t] = s[t] - v;
}
__global__ void k_scan3(const unsigned* __restrict__ rowlocal, const unsigned* __restrict__ boffs,
                        unsigned* __restrict__ rowstart){
    int i = blockIdx.x*256 + threadIdx.x;
    if (i < N_NODES) rowstart[i] = rowlocal[i] + boffs[i>>8];
}
// scatter packed {eid, src, dst} record to CSR position (single 12B store per edge)
__global__ void k_scatter(const int* __restrict__ src, const int* __restrict__ dst,
                          const unsigned* __restrict__ rowstart,
                          unsigned* __restrict__ cursor, ERec* __restrict__ erec){
    int i = blockIdx.x*256 + threadIdx.x;
    if (i < N_EDGES){
        int d = dst[i];
        int s = src[i];
        unsigned pos = rowstart[d] + atomicAdd(&cursor[d], 1u);
        ERec r; r.eid = (unsigned)i; r.sn = (unsigned)s; r.dn = (unsigned)d;
        erec[pos] = r;
    }
}

// ================= edge GEMM via MFMA, all 64 cols, one 16-edge tile per wave ===========
__global__ __launch_bounds__(256) void k_edge(
    const unsigned short* __restrict__ hb, const float* __restrict__ e_in,
    const float* __restrict__ W_pre, const float* __restrict__ b_pre,
    const ERec* __restrict__ erec, unsigned short* __restrict__ mbuf, int pass)
{
    int tid = threadIdx.x;
    int wv = tid>>6, l = tid&63;
    int lr = l&15, lg = l>>4;

    // B-frags: B[k][col], col = cg*16+lr, k = 32*ks + 8*lg + e  (K padded 144->160)
    short8 B[5][4];
    #pragma unroll
    for (int ks=0; ks<5; ks++){
        #pragma unroll
        for (int cg=0; cg<4; cg++){
            short8 b;
            #pragma unroll
            for (int e=0; e<8; e++){
                int k = ks*32 + lg*8 + e;
                b[e] = (k < 144) ? f2b(W_pre[k*64 + cg*16 + lr]) : (short)0;
            }
            B[ks][cg] = b;
        }
    }
    float bias[4];
    #pragma unroll
    for (int cg=0; cg<4; cg++) bias[cg] = b_pre[cg*16 + lr];

    int t = blockIdx.x*4 + wv;                  // grid 6250*4 == TILES_PER_PASS: 1 tile/wave
    if (t >= TILES_PER_PASS) return;
    int gt = pass*TILES_PER_PASS + t;

    ERec r = erec[gt*16 + lr];                  // A row = lr; dense coalesced record
    const unsigned short* ps = hb + (size_t)r.sn*64 + lg*8;
    const unsigned short* pd = hb + (size_t)r.dn*64 + lg*8;
    f32x4 acc[4];
    #pragma unroll
    for (int cg=0; cg<4; cg++) acc[cg] = (f32x4){0.f,0.f,0.f,0.f};

    short8 A;
    A = *(const short8*)ps;                     // ks0: h[src] cols 0..31
    #pragma unroll
    for (int cg=0; cg<4; cg++) acc[cg] = __builtin_amdgcn_mfma_f32_16x16x32_bf16(A, B[0][cg], acc[cg], 0,0,0);
    A = *(const short8*)(ps + 32);              // ks1: h[src] cols 32..63
    #pragma unroll
    for (int cg=0; cg<4; cg++) acc[cg] = __builtin_amdgcn_mfma_f32_16x16x32_bf16(A, B[1][cg], acc[cg], 0,0,0);
    A = *(const short8*)pd;                     // ks2: h[dst] cols 0..31
    #pragma unroll
    for (int cg=0; cg<4; cg++) acc[cg] = __builtin_amdgcn_mfma_f32_16x16x32_bf16(A, B[2][cg], acc[cg], 0,0,0);
    A = *(const short8*)(pd + 32);              // ks3: h[dst] cols 32..63
    #pragma unroll
    for (int cg=0; cg<4; cg++) acc[cg] = __builtin_amdgcn_mfma_f32_16x16x32_bf16(A, B[3][cg], acc[cg], 0,0,0);
    {                                           // ks4: e (k 128..143) + pad
        short8 A4 = {0,0,0,0,0,0,0,0};
        if (lg < 2){
            const float* pe = e_in + (size_t)r.eid*16 + lg*8;
            float4 u0 = *(const float4*)pe, u1 = *(const float4*)(pe+4);
            A4[0]=f2b(u0.x); A4[1]=f2b(u0.y); A4[2]=f2b(u0.z); A4[3]=f2b(u0.w);
            A4[4]=f2b(u1.x); A4[5]=f2b(u1.y); A4[6]=f2b(u1.z); A4[7]=f2b(u1.w);
        }
        #pragma unroll
        for (int cg=0; cg<4; cg++) acc[cg] = __builtin_amdgcn_mfma_f32_16x16x32_bf16(A4, B[4][cg], acc[cg], 0,0,0);
    }
    // D: row = 4*lg + r (local to pass), col = cg*16 + lr
    #pragma unroll
    for (int rr=0; rr<4; rr++){
        size_t row = (size_t)t*16 + lg*4 + rr;
        #pragma unroll
        for (int cg=0; cg<4; cg++)
            mbuf[row*64 + cg*16 + lr] = (unsigned short)f2b(acc[cg][rr] + bias[cg]);
    }
}

// ================= segment aggregation over CSR rows (pass-windowed, carry at splits) ====
__global__ __launch_bounds__(256) void k_agg(
    const unsigned short* __restrict__ mbuf, const unsigned* __restrict__ rowstart,
    const unsigned* __restrict__ deg, unsigned short* __restrict__ agg,
    float* __restrict__ ab, float* __restrict__ carry, int pass)
{
    int wv = threadIdx.x>>6, l = threadIdx.x&63;
    int node = blockIdx.x*4 + wv;                 // grid 25000*4 == N
    int hf = l>>5, c = l&31;                      // lane c handles cols 2c, 2c+1
    unsigned start = rowstart[node];
    int d = (int)deg[node];                       // d >= 1 (dst includes arange(N))
    unsigned end = start + (unsigned)d;
    unsigned lo = (unsigned)pass * ROWS_PER_PASS;
    unsigned hi = lo + ROWS_PER_PASS;
    if (end <= lo || start >= hi) return;
    unsigned a = start < lo ? lo : start;
    unsigned b = end > hi ? hi : end;
    int n = (int)(b - a);
    const unsigned short* p = mbuf + (size_t)(a - lo)*64 + 2*c;
    float s1a=0.f,s2a=0.f,mxa=-3.402823466e38f,mna=3.402823466e38f;
    float s1b=0.f,s2b=0.f,mxb=-3.402823466e38f,mnb=3.402823466e38f;
    for (int i=hf; i<n; i+=2){                    // 2 rows in flight, 256 B/wave-iter
        unsigned v = *(const unsigned*)(p + (size_t)i*64);
        float va = b2f(v & 0xffffu), vb = b2f(v >> 16);
        s1a += va; s2a = fmaf(va,va,s2a); mxa = fmaxf(mxa,va); mna = fminf(mna,va);
        s1b += vb; s2b = fmaf(vb,vb,s2b); mxb = fmaxf(mxb,vb); mnb = fminf(mnb,vb);
    }
    s1a += __shfl_xor(s1a,32); s2a += __shfl_xor(s2a,32);
    mxa = fmaxf(mxa,__shfl_xor(mxa,32)); mna = fminf(mna,__shfl_xor(mna,32));
    s1b += __shfl_xor(s1b,32); s2b += __shfl_xor(s2b,32);
    mxb = fmaxf(mxb,__shfl_xor(mxb,32)); mnb = fminf(mnb,__shfl_xor(mnb,32));
    if (l < 32){
        if (start < lo){                          // merge carry from split (pass-1)
            const float* cb = carry + (size_t)(pass-1)*256;
            s1a += cb[      2*c];   s1b += cb[      2*c+1];
            s2a += cb[ 64 + 2*c];   s2b += cb[ 64 + 2*c+1];
            mxa = fmaxf(mxa, cb[128 + 2*c]); mxb = fmaxf(mxb, cb[128 + 2*c+1]);
            mna = fminf(mna, cb[192 + 2*c]); mnb = fminf(mnb, cb[192 + 2*c+1]);
        }
        if (end > hi){                            // spill partial to carry[pass]
            float* cb = carry + (size_t)pass*256;
            cb[      2*c] = s1a;  cb[      2*c+1] = s1b;
            cb[ 64 + 2*c] = s2a;  cb[ 64 + 2*c+1] = s2b;
            cb[128 + 2*c] = mxa;  cb[128 + 2*c+1] = mxb;
            cb[192 + 2*c] = mna;  cb[192 + 2*c+1] = mnb;
        } else {                                  // finalize
            float D = (float)d;
            float meana = s1a/D, meanb = s1b/D;
            float sda = sqrtf(fmaxf(s2a/D - meana*meana, 0.f) + EPSV);
            float sdb = sqrtf(fmaxf(s2b/D - meanb*meanb, 0.f) + EPSV);
            unsigned* ag = (unsigned*)(agg + (size_t)node*256) + c;  // packed col pair
            ag[ 0] = pk(meana, meanb);
            ag[32] = pk(mxa,  mxb);
            ag[64] = pk(mna,  mnb);
            ag[96] = pk(sda,  sdb);
            if (c == 0){
                float logd = logf(D + 1.f);
                ab[node*2]   = logd / AVG_D;
                ab[node*2+1] = AVG_D / logd;
            }
        }
    }
}

// ================= post GEMM via MFMA: out = [h|agg]@Wm + a*(agg@W2) + b*(agg@W3) =========
__global__ __launch_bounds__(256) void k_post(
    const unsigned short* __restrict__ hb, const unsigned short* __restrict__ agg,
    const float* __restrict__ ab, const float* __restrict__ snorm,
    const float* __restrict__ W_post, const float* __restrict__ b_post,
    float* __restrict__ out_pre, float* __restrict__ bn_acc)
{
    int tid = threadIdx.x;
    int cg = tid>>6;
    int l = tid&63, lr = l&15, lg = l>>4;
    int col = cg*16 + lr;

    short8 Bm[10], B2[8], B3[8];
    #pragma unroll
    for (int ks=0; ks<10; ks++){
        short8 b;
        #pragma unroll
        for (int e=0; e<8; e++){
            int row = ks*32 + lg*8 + e;           // rows 0..319: [h(64) | agg(256)]
            b[e] = f2b(W_post[row*64 + col]);
        }
        Bm[ks] = b;
    }
    #pragma unroll
    for (int ks=0; ks<8; ks++){
        short8 b, c;
        #pragma unroll
        for (int e=0; e<8; e++){
            int row = ks*32 + lg*8 + e;
            b[e] = f2b(W_post[(320+row)*64 + col]);   // a*agg block
            c[e] = f2b(W_post[(576+row)*64 + col]);   // b*agg block
        }
        B2[ks] = b; B3[ks] = c;
    }
    float bias = b_post[col];
    float bs = 0.f, bq = 0.f;

    for (int t = blockIdx.x; t < NT_POST; t += gridDim.x){
        int nodeA = t*16 + lr;                    // A row = lane&15
        f32x4 aM = {0.f,0.f,0.f,0.f}, a2 = {0.f,0.f,0.f,0.f}, a3 = {0.f,0.f,0.f,0.f};
        #pragma unroll
        for (int ks=0; ks<2; ks++){               // h part: direct bf16 load
            short8 A = *(const short8*)(hb + (size_t)nodeA*64 + ks*32 + lg*8);
            aM = __builtin_amdgcn_mfma_f32_16x16x32_bf16(A, Bm[ks], aM, 0,0,0);
        }
        #pragma unroll
        for (int ks=0; ks<8; ks++){               // agg part
            short8 A = *(const short8*)(agg + (size_t)nodeA*256 + ks*32 + lg*8);
            aM = __builtin_amdgcn_mfma_f32_16x16x32_bf16(A, Bm[2+ks], aM, 0,0,0);
            a2 = __builtin_amdgcn_mfma_f32_16x16x32_bf16(A, B2[ks],  a2, 0,0,0);
            a3 = __builtin_amdgcn_mfma_f32_16x16x32_bf16(A, B3[ks],  a3, 0,0,0);
        }
        #pragma unroll
        for (int r=0; r<4; r++){
            int node = t*16 + lg*4 + r;           // D row = 4*lg + r
            float av = ab[node*2], bv = ab[node*2+1];
            float v = (aM[r] + av*a2[r] + bv*a3[r] + bias) * snorm[node];
            out_pre[(size_t)node*64 + col] = v;
            bs += v; bq = fmaf(v,v,bq);
        }
    }
    bs += __shfl_xor(bs, 16); bs += __shfl_xor(bs, 32);
    bq += __shfl_xor(bq, 16); bq += __shfl_xor(bq, 32);
    if (l < 16){
        atomicAdd(&bn_acc[cg*16 + l], bs);
        atomicAdd(&bn_acc[64 + cg*16 + l], bq);
    }
}

// ================= BatchNorm finalize + apply =================
__global__ void k_bnfin(const float* __restrict__ bn_acc, const float* __restrict__ gamma,
                        const float* __restrict__ beta, float* __restrict__ bn_fin){
    int c = threadIdx.x;
    float invN = 1.f/(float)N_NODES;
    float mu = bn_acc[c]*invN;
    float ms = bn_acc[64+c]*invN;
    float var = fmaxf(ms - mu*mu, 0.f);
    float scale = gamma[c] / sqrtf(var + 1e-5f);
    bn_fin[c] = scale;
    bn_fin[64+c] = beta[c] - mu*scale;
}
__global__ void k_apply(const float* __restrict__ out_pre, const float* __restrict__ bn_fin,
                        float* __restrict__ out){
    int i = blockIdx.x*256 + threadIdx.x;     // float4 index; 6250*256*4 == N*64
    int c4 = (i & 15) * 4;
    float4 v  = ((const float4*)out_pre)[i];
    float4 sc = *(const float4*)&bn_fin[c4];
    float4 sh = *(const float4*)&bn_fin[64 + c4];
    float4 o;
    o.x = fmaf(v.x, sc.x, sh.x); o.y = fmaf(v.y, sc.y, sh.y);
    o.z = fmaf(v.z, sc.z, sh.z); o.w = fmaf(v.w, sc.w, sh.w);
    ((float4*)out)[i] = o;
}

extern "C" void kernel_launch(void* const* d_in, const int* in_sizes, int n_in,
                              void* d_out, int out_size, void* d_ws, size_t ws_size,
                              hipStream_t stream)
{
    const float* h      = (const float*)d_in[0];
    const float* e_in   = (const float*)d_in[1];
    const float* snorm  = (const float*)d_in[2];
    const float* W_pre  = (const float*)d_in[3];
    const float* b_pre  = (const float*)d_in[4];
    const float* W_post = (const float*)d_in[5];
    const float* b_post = (const float*)d_in[6];
    const float* gamma  = (const float*)d_in[7];
    const float* beta   = (const float*)d_in[8];
    const int*   src    = (const int*)d_in[9];
    const int*   dst    = (const int*)d_in[10];

    char* ws = (char*)d_ws;
    unsigned* deg      = (unsigned*)(ws + OFF_DEG);
    unsigned* rowlocal = (unsigned*)(ws + OFF_ROWLOCAL);
    unsigned* bsum     = (unsigned*)(ws + OFF_BSUM);
    unsigned* boffs    = (unsigned*)(ws + OFF_BOFFS);
    unsigned* rowstart = (unsigned*)(ws + OFF_ROWSTART);
    unsigned* cursor   = (unsigned*)(ws + OFF_CURSOR);
    ERec*     erec     = (ERec*)(ws + OFF_EREC);
    float*    abuf     = (float*)(ws + OFF_AB);
    float*    bnacc    = (float*)(ws + OFF_BNACC);
    float*    bnfin    = (float*)(ws + OFF_BNFIN);
    unsigned short* hb   = (unsigned short*)(ws + OFF_HB);
    unsigned short* mbuf = (unsigned short*)(ws + OFF_MBUF);
    unsigned short* aggp = (unsigned short*)(ws + OFF_AGG);
    float*    carry    = (float*)(ws + OFF_CARRY);
    float*    outpre   = (float*)(ws + OFF_OUTPRE);

    hipMemsetAsync(ws + OFF_DEG,    0, 400000, stream);
    hipMemsetAsync(ws + OFF_CURSOR, 0, 400000, stream);
    hipMemsetAsync(ws + OFF_BNACC,  0, 512,    stream);

    k_prep   <<<4688, 256, 0, stream>>>(dst, deg, h, hb);
    k_scan1  <<<391,  256, 0, stream>>>(deg, rowlocal, bsum);
    k_scan2  <<<1,    512, 0, stream>>>(bsum, boffs);
    k_scan3  <<<391,  256, 0, stream>>>(rowlocal, boffs, rowstart);
    k_scatter<<<4688, 256, 0, stream>>>(src, dst, rowstart, cursor, erec);

    for (int pass = 0; pass < NPASS; pass++){
        k_edge <<<6250, 256, 0, stream>>>(hb, e_in, W_pre, b_pre, erec, mbuf, pass);
        k_agg  <<<25000,256, 0, stream>>>(mbuf, rowstart, deg, aggp, abuf, carry, pass);
    }

    k_post   <<<1024, 256, 0, stream>>>(hb, aggp, abuf, snorm, W_post, b_post, outpre, bnacc);
    k_bnfin  <<<1,    64,  0, stream>>>(bnacc, gamma, beta, bnfin);
    k_apply  <<<6250, 256, 0, stream>>>(outpre, bnfin, (float*)d_out);
}

// Round 6
// 620.298 us; speedup vs baseline: 1.1792x; 1.1792x over previous
//
#include <hip/hip_runtime.h>
#include <hip/hip_bf16.h>
#include <math.h>

#define N_NODES 100000
#define N_EDGES 1200000
#define NT_EDGE 75000          // total 16-edge tiles
#define NPASS   3
#define TILES_PER_PASS 25000   // NT_EDGE / NPASS
#define ROWS_PER_PASS  400000  // TILES_PER_PASS * 16
#define NT_POST 6250           // node tiles of 16
#define AVG_D   2.5649493574615367f
#define EPSV    1e-5f

typedef __attribute__((ext_vector_type(8))) short short8;
typedef __attribute__((ext_vector_type(4))) float f32x4;

struct ERec { unsigned eid, sn, dn; };   // 12 B packed CSR record

// ---- workspace layout (bytes), total 132,005,120 (< 135,205,120 proven) ----
#define OFF_DEG       0u
#define OFF_ROWLOCAL  400000u
#define OFF_BSUM      800000u         // 2048; dead after scans -> reused as CARRY
#define OFF_BOFFS     802048u
#define OFF_ROWSTART  804096u
#define OFF_CURSOR    1204096u
#define OFF_EREC      1604096u        // E * 12 B = 14.4 MB
#define OFF_AB        16004096u       // N*2 f32
#define OFF_BNACC     16804096u       // 128 f32
#define OFF_BNFIN     16804608u       // 128 f32
#define OFF_HB        16805120u       // N*64 bf16 = 12.8 MB
#define OFF_MBUF      29605120u       // 400000 rows * 64 bf16 = 51.2 MB
#define OFF_AGG       80805120u       // N*256 bf16 = 51.2 MB  (end 132,005,120)
#define OFF_CARRY     OFF_BSUM        // 2 splits * 4 stats * 64 f32 = 2048 B
#define OFF_OUTPRE    OFF_MBUF        // N*64 f32 = 25.6 MB, mbuf dead by k_post

__device__ __forceinline__ short f2b(float f){          // fp32 -> bf16 bits (RNE)
    union { float f; unsigned u; } c; c.f = f;
    unsigned u = c.u;
    unsigned r = (u + 0x7fffu + ((u >> 16) & 1u)) >> 16;
    return (short)r;
}
__device__ __forceinline__ float b2f(unsigned u16){     // bf16 bits (low 16) -> fp32
    union { unsigned u; float f; } c; c.u = u16 << 16;
    return c.f;
}
__device__ __forceinline__ unsigned pk(float a, float b){
    return ((unsigned)(unsigned short)f2b(a)) | (((unsigned)(unsigned short)f2b(b)) << 16);
}

// ================= CSR build + h->bf16 conversion =================
__global__ void k_prep(const int* __restrict__ dst, unsigned* __restrict__ deg,
                       const float* __restrict__ h, unsigned short* __restrict__ hb){
    int i = blockIdx.x*256 + threadIdx.x;
    if (i < N_EDGES) atomicAdd(&deg[dst[i]], 1u);
    if (i < 800000){                                    // 8 floats per thread
        const float4* p = (const float4*)h + (size_t)i*2;
        float4 u0 = p[0], u1 = p[1];
        uint4 o;
        o.x = pk(u0.x,u0.y); o.y = pk(u0.z,u0.w);
        o.z = pk(u1.x,u1.y); o.w = pk(u1.z,u1.w);
        ((uint4*)hb)[i] = o;
    }
}
__global__ void k_scan1(const unsigned* __restrict__ deg, unsigned* __restrict__ rowlocal,
                        unsigned* __restrict__ bsum){
    __shared__ unsigned s[256];
    int t = threadIdx.x; int i = blockIdx.x*256 + t;
    unsigned d = (i < N_NODES) ? deg[i] : 0u;
    s[t] = d; __syncthreads();
    for (int off=1; off<256; off<<=1){
        unsigned v = (t>=off) ? s[t-off] : 0u; __syncthreads();
        s[t] += v; __syncthreads();
    }
    if (i < N_NODES) rowlocal[i] = s[t] - d;
    if (t == 255) bsum[blockIdx.x] = s[255];
}
__global__ void k_scan2(const unsigned* __restrict__ bsum, unsigned* __restrict__ boffs){
    __shared__ unsigned s[512];
    int t = threadIdx.x;
    unsigned v = (t < 391) ? bsum[t] : 0u;
    s[t] = v; __syncthreads();
    for (int off=1; off<512; off<<=1){
        unsigned x = (t>=off) ? s[t-off] : 0u; __syncthreads();
        s[t] += x; __syncthreads();
    }
    boffs[t] = s[t] - v;
}
__global__ void k_scan3(const unsigned* __restrict__ rowlocal, const unsigned* __restrict__ boffs,
                        unsigned* __restrict__ rowstart){
    int i = blockIdx.x*256 + threadIdx.x;
    if (i < N_NODES) rowstart[i] = rowlocal[i] + boffs[i>>8];
}
// scatter packed {eid, src, dst} record to CSR position (single 12B store per edge)
__global__ void k_scatter(const int* __restrict__ src, const int* __restrict__ dst,
                          const unsigned* __restrict__ rowstart,
                          unsigned* __restrict__ cursor, ERec* __restrict__ erec){
    int i = blockIdx.x*256 + threadIdx.x;
    if (i < N_EDGES){
        int d = dst[i];
        int s = src[i];
        unsigned pos = rowstart[d] + atomicAdd(&cursor[d], 1u);
        ERec r; r.eid = (unsigned)i; r.sn = (unsigned)s; r.dn = (unsigned)d;
        erec[pos] = r;
    }
}

// ================= edge GEMM via MFMA: grid-stride tiles + erec prefetch pipeline =========
__global__ __launch_bounds__(256) void k_edge(
    const unsigned short* __restrict__ hb, const float* __restrict__ e_in,
    const float* __restrict__ W_pre, const float* __restrict__ b_pre,
    const ERec* __restrict__ erec, unsigned short* __restrict__ mbuf, int pass)
{
    int tid = threadIdx.x;
    int wv = tid>>6, l = tid&63;
    int lr = l&15, lg = l>>4;

    // B-frags: B[k][col], col = cg*16+lr, k = 32*ks + 8*lg + e  (K padded 144->160)
    short8 B[5][4];
    #pragma unroll
    for (int ks=0; ks<5; ks++){
        #pragma unroll
        for (int cg=0; cg<4; cg++){
            short8 b;
            #pragma unroll
            for (int e=0; e<8; e++){
                int k = ks*32 + lg*8 + e;
                b[e] = (k < 144) ? f2b(W_pre[k*64 + cg*16 + lr]) : (short)0;
            }
            B[ks][cg] = b;
        }
    }
    float bias[4];
    #pragma unroll
    for (int cg=0; cg<4; cg++) bias[cg] = b_pre[cg*16 + lr];

    const ERec* er = erec + (size_t)pass*ROWS_PER_PASS;
    int gw = blockIdx.x*4 + wv;                 // grid 2084*4 = 8336 waves -> ~3 tiles/wave
    int nw = gridDim.x*4;

    if (gw >= TILES_PER_PASS) return;
    ERec r = er[gw*16 + lr];                    // stage-0 prefetch

    for (int t = gw; t < TILES_PER_PASS; t += nw){
        // --- issue all gathers for current tile (independent once r is here) ---
        const unsigned short* ps = hb + (size_t)r.sn*64 + lg*8;
        const unsigned short* pd = hb + (size_t)r.dn*64 + lg*8;
        short8 A0 = *(const short8*)ps;          // h[src] cols 0..31
        short8 A1 = *(const short8*)(ps + 32);   // h[src] cols 32..63
        short8 A2 = *(const short8*)pd;          // h[dst] cols 0..31
        short8 A3 = *(const short8*)(pd + 32);   // h[dst] cols 32..63
        float4 u0 = {0,0,0,0}, u1 = {0,0,0,0};
        if (lg < 2){
            const float* pe = e_in + (size_t)r.eid*16 + lg*8;
            u0 = *(const float4*)pe; u1 = *(const float4*)(pe+4);
        }
        // --- prefetch next tile's record; hides erec latency under MFMA block ---
        int tn = t + nw;
        if (tn < TILES_PER_PASS) r = er[tn*16 + lr];

        f32x4 acc[4];
        #pragma unroll
        for (int cg=0; cg<4; cg++) acc[cg] = (f32x4){0.f,0.f,0.f,0.f};
        #pragma unroll
        for (int cg=0; cg<4; cg++) acc[cg] = __builtin_amdgcn_mfma_f32_16x16x32_bf16(A0, B[0][cg], acc[cg], 0,0,0);
        #pragma unroll
        for (int cg=0; cg<4; cg++) acc[cg] = __builtin_amdgcn_mfma_f32_16x16x32_bf16(A1, B[1][cg], acc[cg], 0,0,0);
        #pragma unroll
        for (int cg=0; cg<4; cg++) acc[cg] = __builtin_amdgcn_mfma_f32_16x16x32_bf16(A2, B[2][cg], acc[cg], 0,0,0);
        #pragma unroll
        for (int cg=0; cg<4; cg++) acc[cg] = __builtin_amdgcn_mfma_f32_16x16x32_bf16(A3, B[3][cg], acc[cg], 0,0,0);
        {                                        // ks4: e (k 128..143) + pad
            short8 A4 = {0,0,0,0,0,0,0,0};
            if (lg < 2){
                A4[0]=f2b(u0.x); A4[1]=f2b(u0.y); A4[2]=f2b(u0.z); A4[3]=f2b(u0.w);
                A4[4]=f2b(u1.x); A4[5]=f2b(u1.y); A4[6]=f2b(u1.z); A4[7]=f2b(u1.w);
            }
            #pragma unroll
            for (int cg=0; cg<4; cg++) acc[cg] = __builtin_amdgcn_mfma_f32_16x16x32_bf16(A4, B[4][cg], acc[cg], 0,0,0);
        }
        // D: row = 4*lg + rr (local to pass), col = cg*16 + lr
        #pragma unroll
        for (int rr=0; rr<4; rr++){
            size_t row = (size_t)t*16 + lg*4 + rr;
            #pragma unroll
            for (int cg=0; cg<4; cg++)
                mbuf[row*64 + cg*16 + lr] = (unsigned short)f2b(acc[cg][rr] + bias[cg]);
        }
    }
}

// ================= segment aggregation over CSR rows (pass-windowed, carry at splits) ====
__global__ __launch_bounds__(256) void k_agg(
    const unsigned short* __restrict__ mbuf, const unsigned* __restrict__ rowstart,
    const unsigned* __restrict__ deg, unsigned short* __restrict__ agg,
    float* __restrict__ ab, float* __restrict__ carry, int pass)
{
    int wv = threadIdx.x>>6, l = threadIdx.x&63;
    int node = blockIdx.x*4 + wv;                 // grid 25000*4 == N
    int hf = l>>5, c = l&31;                      // lane c handles cols 2c, 2c+1
    unsigned start = rowstart[node];
    int d = (int)deg[node];                       // d >= 1 (dst includes arange(N))
    unsigned end = start + (unsigned)d;
    unsigned lo = (unsigned)pass * ROWS_PER_PASS;
    unsigned hi = lo + ROWS_PER_PASS;
    if (end <= lo || start >= hi) return;
    unsigned a = start < lo ? lo : start;
    unsigned b = end > hi ? hi : end;
    int n = (int)(b - a);
    const unsigned short* p = mbuf + (size_t)(a - lo)*64 + 2*c;
    float s1a=0.f,s2a=0.f,mxa=-3.402823466e38f,mna=3.402823466e38f;
    float s1b=0.f,s2b=0.f,mxb=-3.402823466e38f,mnb=3.402823466e38f;
    for (int i=hf; i<n; i+=2){                    // 2 rows in flight, 256 B/wave-iter
        unsigned v = *(const unsigned*)(p + (size_t)i*64);
        float va = b2f(v & 0xffffu), vb = b2f(v >> 16);
        s1a += va; s2a = fmaf(va,va,s2a); mxa = fmaxf(mxa,va); mna = fminf(mna,va);
        s1b += vb; s2b = fmaf(vb,vb,s2b); mxb = fmaxf(mxb,vb); mnb = fminf(mnb,vb);
    }
    s1a += __shfl_xor(s1a,32); s2a += __shfl_xor(s2a,32);
    mxa = fmaxf(mxa,__shfl_xor(mxa,32)); mna = fminf(mna,__shfl_xor(mna,32));
    s1b += __shfl_xor(s1b,32); s2b += __shfl_xor(s2b,32);
    mxb = fmaxf(mxb,__shfl_xor(mxb,32)); mnb = fminf(mnb,__shfl_xor(mnb,32));
    if (l < 32){
        if (start < lo){                          // merge carry from split (pass-1)
            const float* cb = carry + (size_t)(pass-1)*256;
            s1a += cb[      2*c];   s1b += cb[      2*c+1];
            s2a += cb[ 64 + 2*c];   s2b += cb[ 64 + 2*c+1];
            mxa = fmaxf(mxa, cb[128 + 2*c]); mxb = fmaxf(mxb, cb[128 + 2*c+1]);
            mna = fminf(mna, cb[192 + 2*c]); mnb = fminf(mnb, cb[192 + 2*c+1]);
        }
        if (end > hi){                            // spill partial to carry[pass]
            float* cb = carry + (size_t)pass*256;
            cb[      2*c] = s1a;  cb[      2*c+1] = s1b;
            cb[ 64 + 2*c] = s2a;  cb[ 64 + 2*c+1] = s2b;
            cb[128 + 2*c] = mxa;  cb[128 + 2*c+1] = mxb;
            cb[192 + 2*c] = mna;  cb[192 + 2*c+1] = mnb;
        } else {                                  // finalize
            float D = (float)d;
            float meana = s1a/D, meanb = s1b/D;
            float sda = sqrtf(fmaxf(s2a/D - meana*meana, 0.f) + EPSV);
            float sdb = sqrtf(fmaxf(s2b/D - meanb*meanb, 0.f) + EPSV);
            unsigned* ag = (unsigned*)(agg + (size_t)node*256) + c;  // packed col pair
            ag[ 0] = pk(meana, meanb);
            ag[32] = pk(mxa,  mxb);
            ag[64] = pk(mna,  mnb);
            ag[96] = pk(sda,  sdb);
            if (c == 0){
                float logd = logf(D + 1.f);
                ab[node*2]   = logd / AVG_D;
                ab[node*2+1] = AVG_D / logd;
            }
        }
    }
}

// ================= post GEMM via MFMA: out = [h|agg]@Wm + a*(agg@W2) + b*(agg@W3) =========
__global__ __launch_bounds__(256) void k_post(
    const unsigned short* __restrict__ hb, const unsigned short* __restrict__ agg,
    const float* __restrict__ ab, const float* __restrict__ snorm,
    const float* __restrict__ W_post, const float* __restrict__ b_post,
    float* __restrict__ out_pre, float* __restrict__ bn_acc)
{
    int tid = threadIdx.x;
    int cg = tid>>6;
    int l = tid&63, lr = l&15, lg = l>>4;
    int col = cg*16 + lr;

    short8 Bm[10], B2[8], B3[8];
    #pragma unroll
    for (int ks=0; ks<10; ks++){
        short8 b;
        #pragma unroll
        for (int e=0; e<8; e++){
            int row = ks*32 + lg*8 + e;           // rows 0..319: [h(64) | agg(256)]
            b[e] = f2b(W_post[row*64 + col]);
        }
        Bm[ks] = b;
    }
    #pragma unroll
    for (int ks=0; ks<8; ks++){
        short8 b, c;
        #pragma unroll
        for (int e=0; e<8; e++){
            int row = ks*32 + lg*8 + e;
            b[e] = f2b(W_post[(320+row)*64 + col]);   // a*agg block
            c[e] = f2b(W_post[(576+row)*64 + col]);   // b*agg block
        }
        B2[ks] = b; B3[ks] = c;
    }
    float bias = b_post[col];
    float bs = 0.f, bq = 0.f;

    for (int t = blockIdx.x; t < NT_POST; t += gridDim.x){
        int nodeA = t*16 + lr;                    // A row = lane&15
        f32x4 aM = {0.f,0.f,0.f,0.f}, a2 = {0.f,0.f,0.f,0.f}, a3 = {0.f,0.f,0.f,0.f};
        #pragma unroll
        for (int ks=0; ks<2; ks++){               // h part: direct bf16 load
            short8 A = *(const short8*)(hb + (size_t)nodeA*64 + ks*32 + lg*8);
            aM = __builtin_amdgcn_mfma_f32_16x16x32_bf16(A, Bm[ks], aM, 0,0,0);
        }
        #pragma unroll
        for (int ks=0; ks<8; ks++){               // agg part
            short8 A = *(const short8*)(agg + (size_t)nodeA*256 + ks*32 + lg*8);
            aM = __builtin_amdgcn_mfma_f32_16x16x32_bf16(A, Bm[2+ks], aM, 0,0,0);
            a2 = __builtin_amdgcn_mfma_f32_16x16x32_bf16(A, B2[ks],  a2, 0,0,0);
            a3 = __builtin_amdgcn_mfma_f32_16x16x32_bf16(A, B3[ks],  a3, 0,0,0);
        }
        #pragma unroll
        for (int r=0; r<4; r++){
            int node = t*16 + lg*4 + r;           // D row = 4*lg + r
            float av = ab[node*2], bv = ab[node*2+1];
            float v = (aM[r] + av*a2[r] + bv*a3[r] + bias) * snorm[node];
            out_pre[(size_t)node*64 + col] = v;
            bs += v; bq = fmaf(v,v,bq);
        }
    }
    bs += __shfl_xor(bs, 16); bs += __shfl_xor(bs, 32);
    bq += __shfl_xor(bq, 16); bq += __shfl_xor(bq, 32);
    if (l < 16){
        atomicAdd(&bn_acc[cg*16 + l], bs);
        atomicAdd(&bn_acc[64 + cg*16 + l], bq);
    }
}

// ================= BatchNorm finalize + apply =================
__global__ void k_bnfin(const float* __restrict__ bn_acc, const float* __restrict__ gamma,
                        const float* __restrict__ beta, float* __restrict__ bn_fin){
    int c = threadIdx.x;
    float invN = 1.f/(float)N_NODES;
    float mu = bn_acc[c]*invN;
    float ms = bn_acc[64+c]*invN;
    float var = fmaxf(ms - mu*mu, 0.f);
    float scale = gamma[c] / sqrtf(var + 1e-5f);
    bn_fin[c] = scale;
    bn_fin[64+c] = beta[c] - mu*scale;
}
__global__ void k_apply(const float* __restrict__ out_pre, const float* __restrict__ bn_fin,
                        float* __restrict__ out){
    int i = blockIdx.x*256 + threadIdx.x;     // float4 index; 6250*256*4 == N*64
    int c4 = (i & 15) * 4;
    float4 v  = ((const float4*)out_pre)[i];
    float4 sc = *(const float4*)&bn_fin[c4];
    float4 sh = *(const float4*)&bn_fin[64 + c4];
    float4 o;
    o.x = fmaf(v.x, sc.x, sh.x); o.y = fmaf(v.y, sc.y, sh.y);
    o.z = fmaf(v.z, sc.z, sh.z); o.w = fmaf(v.w, sc.w, sh.w);
    ((float4*)out)[i] = o;
}

extern "C" void kernel_launch(void* const* d_in, const int* in_sizes, int n_in,
                              void* d_out, int out_size, void* d_ws, size_t ws_size,
                              hipStream_t stream)
{
    const float* h      = (const float*)d_in[0];
    const float* e_in   = (const float*)d_in[1];
    const float* snorm  = (const float*)d_in[2];
    const float* W_pre  = (const float*)d_in[3];
    const float* b_pre  = (const float*)d_in[4];
    const float* W_post = (const float*)d_in[5];
    const float* b_post = (const float*)d_in[6];
    const float* gamma  = (const float*)d_in[7];
    const float* beta   = (const float*)d_in[8];
    const int*   src    = (const int*)d_in[9];
    const int*   dst    = (const int*)d_in[10];

    char* ws = (char*)d_ws;
    unsigned* deg      = (unsigned*)(ws + OFF_DEG);
    unsigned* rowlocal = (unsigned*)(ws + OFF_ROWLOCAL);
    unsigned* bsum     = (unsigned*)(ws + OFF_BSUM);
    unsigned* boffs    = (unsigned*)(ws + OFF_BOFFS);
    unsigned* rowstart = (unsigned*)(ws + OFF_ROWSTART);
    unsigned* cursor   = (unsigned*)(ws + OFF_CURSOR);
    ERec*     erec     = (ERec*)(ws + OFF_EREC);
    float*    abuf     = (float*)(ws + OFF_AB);
    float*    bnacc    = (float*)(ws + OFF_BNACC);
    float*    bnfin    = (float*)(ws + OFF_BNFIN);
    unsigned short* hb   = (unsigned short*)(ws + OFF_HB);
    unsigned short* mbuf = (unsigned short*)(ws + OFF_MBUF);
    unsigned short* aggp = (unsigned short*)(ws + OFF_AGG);
    float*    carry    = (float*)(ws + OFF_CARRY);
    float*    outpre   = (float*)(ws + OFF_OUTPRE);

    hipMemsetAsync(ws + OFF_DEG,    0, 400000, stream);
    hipMemsetAsync(ws + OFF_CURSOR, 0, 400000, stream);
    hipMemsetAsync(ws + OFF_BNACC,  0, 512,    stream);

    k_prep   <<<4688, 256, 0, stream>>>(dst, deg, h, hb);
    k_scan1  <<<391,  256, 0, stream>>>(deg, rowlocal, bsum);
    k_scan2  <<<1,    512, 0, stream>>>(bsum, boffs);
    k_scan3  <<<391,  256, 0, stream>>>(rowlocal, boffs, rowstart);
    k_scatter<<<4688, 256, 0, stream>>>(src, dst, rowstart, cursor, erec);

    for (int pass = 0; pass < NPASS; pass++){
        k_edge <<<2084, 256, 0, stream>>>(hb, e_in, W_pre, b_pre, erec, mbuf, pass);
        k_agg  <<<25000,256, 0, stream>>>(mbuf, rowstart, deg, aggp, abuf, carry, pass);
    }

    k_post   <<<1024, 256, 0, stream>>>(hb, aggp, abuf, snorm, W_post, b_post, outpre, bnacc);
    k_bnfin  <<<1,    64,  0, stream>>>(bnacc, gamma, beta, bnfin);
    k_apply  <<<6250, 256, 0, stream>>>(outpre, bnfin, (float*)d_out);
}

// Round 7
// 535.801 us; speedup vs baseline: 1.3651x; 1.1577x over previous
//
#include <hip/hip_runtime.h>
#include <hip/hip_bf16.h>
#include <math.h>

#define N_NODES 100000
#define N_EDGES 1200000
#define NT_EDGE 75000          // total 16-edge tiles
#define NPASS   3
#define TILES_PER_PASS 25000   // NT_EDGE / NPASS
#define ROWS_PER_PASS  400000  // TILES_PER_PASS * 16
#define NT_POST 6250           // node tiles of 16
#define AVG_D   2.5649493574615367f
#define EPSV    1e-5f

typedef __attribute__((ext_vector_type(8))) short short8;
typedef __attribute__((ext_vector_type(4))) float f32x4;

struct ERec { unsigned eid, sn, dn; };   // 12 B packed CSR record

// ---- workspace layout (bytes), total 132,132,096 (< 135,205,120 proven) ----
#define OFF_DEG       0u
#define OFF_ROWLOCAL  400000u
#define OFF_BSUM      800000u         // 2048; dead after scans -> reused as CARRY
#define OFF_BOFFS     802048u
#define OFF_ROWSTART  804096u
#define OFF_CURSOR    1204096u
#define OFF_EREC      1604096u        // E * 12 B = 14.4 MB
#define OFF_AB        16004096u       // N*2 f32
#define OFF_BNACC     16804096u       // 128 f32
#define OFF_BNFIN     16804608u       // 128 f32
#define OFF_HB        16805120u       // N*64 bf16 = 12.8 MB
#define OFF_MBUF      29605120u       // 400000 rows * 64 bf16 = 51.2 MB
#define OFF_AGG       80805120u       // N*256 bf16 = 51.2 MB
#define OFF_WFRAG     132005120u      // 5*4*64*8 bf16 = 20,480 B  (k_edge B-frags)
#define OFF_WFRAG2    132025600u      // 26*4*64*8 bf16 = 106,496 B (k_post B-frags)
#define OFF_CARRY     OFF_BSUM        // 2 splits * 4 stats * 64 f32 = 2048 B
#define OFF_OUTPRE    OFF_MBUF        // N*64 f32 = 25.6 MB, mbuf dead by k_post

__device__ __forceinline__ short f2b(float f){          // fp32 -> bf16 bits (RNE)
    union { float f; unsigned u; } c; c.f = f;
    unsigned u = c.u;
    unsigned r = (u + 0x7fffu + ((u >> 16) & 1u)) >> 16;
    return (short)r;
}
__device__ __forceinline__ float b2f(unsigned u16){     // bf16 bits (low 16) -> fp32
    union { unsigned u; float f; } c; c.u = u16 << 16;
    return c.f;
}
__device__ __forceinline__ unsigned pk(float a, float b){
    return ((unsigned)(unsigned short)f2b(a)) | (((unsigned)(unsigned short)f2b(b)) << 16);
}

// ========== CSR build + h->bf16 + weight-fragment precompute ==========
__global__ void k_prep(const int* __restrict__ dst, unsigned* __restrict__ deg,
                       const float* __restrict__ h, unsigned short* __restrict__ hb,
                       const float* __restrict__ W_pre, unsigned short* __restrict__ wfrag,
                       const float* __restrict__ W_post, unsigned short* __restrict__ wfrag2){
    int i = blockIdx.x*256 + threadIdx.x;
    if (i < N_EDGES) atomicAdd(&deg[dst[i]], 1u);
    if (i < 800000){                                    // 8 floats per thread
        const float4* p = (const float4*)h + (size_t)i*2;
        float4 u0 = p[0], u1 = p[1];
        uint4 o;
        o.x = pk(u0.x,u0.y); o.y = pk(u0.z,u0.w);
        o.z = pk(u1.x,u1.y); o.w = pk(u1.z,u1.w);
        ((uint4*)hb)[i] = o;
    }
    // W_pre fragments: layout ((ks*4+cg)*64 + lane)*8 + e ; K padded 144->160
    if (i < 10240){
        int e = i & 7, l = (i>>3) & 63, q = i>>9;       // q = ks*4+cg
        int ks = q>>2, cg = q&3;
        int lr = l&15, lg = l>>4;
        int k = ks*32 + lg*8 + e, col = cg*16 + lr;
        wfrag[i] = (unsigned short)((k < 144) ? f2b(W_pre[k*64 + col]) : (short)0);
    }
    // W_post fragments: layout ((f*4+cg)*64 + lane)*8 + e ; f<10:Bm, 10..17:B2, 18..25:B3
    if (i < 53248){
        int e = i & 7, l = (i>>3) & 63, g = i>>9;       // g = f*4+cg
        int cg = g & 3, f = g>>2;
        int lr = l&15, lg = l>>4;
        int col = cg*16 + lr;
        int row;
        if      (f < 10) row = f*32        + lg*8 + e;
        else if (f < 18) row = 320 + (f-10)*32 + lg*8 + e;
        else             row = 576 + (f-18)*32 + lg*8 + e;
        wfrag2[i] = (unsigned short)f2b(W_post[row*64 + col]);
    }
}
__global__ void k_scan1(const unsigned* __restrict__ deg, unsigned* __restrict__ rowlocal,
                        unsigned* __restrict__ bsum){
    __shared__ unsigned s[256];
    int t = threadIdx.x; int i = blockIdx.x*256 + t;
    unsigned d = (i < N_NODES) ? deg[i] : 0u;
    s[t] = d; __syncthreads();
    for (int off=1; off<256; off<<=1){
        unsigned v = (t>=off) ? s[t-off] : 0u; __syncthreads();
        s[t] += v; __syncthreads();
    }
    if (i < N_NODES) rowlocal[i] = s[t] - d;
    if (t == 255) bsum[blockIdx.x] = s[255];
}
__global__ void k_scan2(const unsigned* __restrict__ bsum, unsigned* __restrict__ boffs){
    __shared__ unsigned s[512];
    int t = threadIdx.x;
    unsigned v = (t < 391) ? bsum[t] : 0u;
    s[t] = v; __syncthreads();
    for (int off=1; off<512; off<<=1){
        unsigned x = (t>=off) ? s[t-off] : 0u; __syncthreads();
        s[t] += x; __syncthreads();
    }
    boffs[t] = s[t] - v;
}
__global__ void k_scan3(const unsigned* __restrict__ rowlocal, const unsigned* __restrict__ boffs,
                        unsigned* __restrict__ rowstart){
    int i = blockIdx.x*256 + threadIdx.x;
    if (i < N_NODES) rowstart[i] = rowlocal[i] + boffs[i>>8];
}
// scatter packed {eid, src, dst} record; non-temporal stores (L2-bypass experiment)
__global__ void k_scatter(const int* __restrict__ src, const int* __restrict__ dst,
                          const unsigned* __restrict__ rowstart,
                          unsigned* __restrict__ cursor, ERec* __restrict__ erec){
    int i = blockIdx.x*256 + threadIdx.x;
    if (i < N_EDGES){
        int d = dst[i];
        int s = src[i];
        unsigned pos = rowstart[d] + atomicAdd(&cursor[d], 1u);
        unsigned* p = (unsigned*)&erec[pos];
        __builtin_nontemporal_store((unsigned)i, p);
        __builtin_nontemporal_store((unsigned)s, p+1);
        __builtin_nontemporal_store((unsigned)d, p+2);
    }
}

// ========== edge GEMM via MFMA: 1 tile/wave, B-frags via LDS ==========
__global__ __launch_bounds__(256) void k_edge(
    const unsigned short* __restrict__ hb, const float* __restrict__ e_in,
    const unsigned short* __restrict__ wfrag, const float* __restrict__ b_pre,
    const ERec* __restrict__ erec, unsigned short* __restrict__ mbuf, int pass)
{
    __shared__ __align__(16) uint4 wfl[1280];            // 20,480 B = 20 frag-groups
    int tid = threadIdx.x;
    int wv = tid>>6, l = tid&63;
    int lr = l&15, lg = l>>4;

    int t = blockIdx.x*4 + wv;                           // grid 6250*4 == TILES_PER_PASS
    const ERec* er = erec + (size_t)pass*ROWS_PER_PASS;
    ERec r = er[(size_t)t*16 + lr];                      // issue gather chain head early

    for (int j=tid; j<1280; j+=256) wfl[j] = ((const uint4*)wfrag)[j];
    __syncthreads();

    const unsigned short* ps = hb + (size_t)r.sn*64 + lg*8;
    const unsigned short* pd = hb + (size_t)r.dn*64 + lg*8;
    short8 A[5];
    A[0] = *(const short8*)ps;                           // h[src] cols 0..31
    A[1] = *(const short8*)(ps + 32);                    // h[src] cols 32..63
    A[2] = *(const short8*)pd;                           // h[dst] cols 0..31
    A[3] = *(const short8*)(pd + 32);                    // h[dst] cols 32..63
    {
        short8 A4 = {0,0,0,0,0,0,0,0};
        if (lg < 2){
            const float* pe = e_in + (size_t)r.eid*16 + lg*8;
            float4 u0 = *(const float4*)pe, u1 = *(const float4*)(pe+4);
            A4[0]=f2b(u0.x); A4[1]=f2b(u0.y); A4[2]=f2b(u0.z); A4[3]=f2b(u0.w);
            A4[4]=f2b(u1.x); A4[5]=f2b(u1.y); A4[6]=f2b(u1.z); A4[7]=f2b(u1.w);
        }
        A[4] = A4;
    }

    f32x4 acc[4];
    #pragma unroll
    for (int cg=0; cg<4; cg++) acc[cg] = (f32x4){0.f,0.f,0.f,0.f};
    #pragma unroll
    for (int ks=0; ks<5; ks++){
        #pragma unroll
        for (int cg=0; cg<4; cg++){
            short8 b = ((const short8*)wfl)[(ks*4+cg)*64 + l];   // ds_read_b128
            acc[cg] = __builtin_amdgcn_mfma_f32_16x16x32_bf16(A[ks], b, acc[cg], 0,0,0);
        }
    }
    float bias[4];
    #pragma unroll
    for (int cg=0; cg<4; cg++) bias[cg] = b_pre[cg*16 + lr];
    #pragma unroll
    for (int rr=0; rr<4; rr++){
        size_t row = (size_t)t*16 + lg*4 + rr;
        #pragma unroll
        for (int cg=0; cg<4; cg++)
            mbuf[row*64 + cg*16 + lr] = (unsigned short)f2b(acc[cg][rr] + bias[cg]);
    }
}

// ========== segment aggregation over CSR rows (pass-windowed, carry at splits) ==========
__global__ __launch_bounds__(256) void k_agg(
    const unsigned short* __restrict__ mbuf, const unsigned* __restrict__ rowstart,
    const unsigned* __restrict__ deg, unsigned short* __restrict__ agg,
    float* __restrict__ ab, float* __restrict__ carry, int pass)
{
    int wv = threadIdx.x>>6, l = threadIdx.x&63;
    int node = blockIdx.x*4 + wv;                 // grid 25000*4 == N
    int hf = l>>5, c = l&31;                      // lane c handles cols 2c, 2c+1
    unsigned start = rowstart[node];
    int d = (int)deg[node];                       // d >= 1 (dst includes arange(N))
    unsigned end = start + (unsigned)d;
    unsigned lo = (unsigned)pass * ROWS_PER_PASS;
    unsigned hi = lo + ROWS_PER_PASS;
    if (end <= lo || start >= hi) return;
    unsigned a = start < lo ? lo : start;
    unsigned b = end > hi ? hi : end;
    int n = (int)(b - a);
    const unsigned short* p = mbuf + (size_t)(a - lo)*64 + 2*c;
    float s1a=0.f,s2a=0.f,mxa=-3.402823466e38f,mna=3.402823466e38f;
    float s1b=0.f,s2b=0.f,mxb=-3.402823466e38f,mnb=3.402823466e38f;
    for (int i=hf; i<n; i+=2){                    // 2 rows in flight, 256 B/wave-iter
        unsigned v = *(const unsigned*)(p + (size_t)i*64);
        float va = b2f(v & 0xffffu), vb = b2f(v >> 16);
        s1a += va; s2a = fmaf(va,va,s2a); mxa = fmaxf(mxa,va); mna = fminf(mna,va);
        s1b += vb; s2b = fmaf(vb,vb,s2b); mxb = fmaxf(mxb,vb); mnb = fminf(mnb,vb);
    }
    s1a += __shfl_xor(s1a,32); s2a += __shfl_xor(s2a,32);
    mxa = fmaxf(mxa,__shfl_xor(mxa,32)); mna = fminf(mna,__shfl_xor(mna,32));
    s1b += __shfl_xor(s1b,32); s2b += __shfl_xor(s2b,32);
    mxb = fmaxf(mxb,__shfl_xor(mxb,32)); mnb = fminf(mnb,__shfl_xor(mnb,32));
    if (l < 32){
        if (start < lo){                          // merge carry from split (pass-1)
            const float* cb = carry + (size_t)(pass-1)*256;
            s1a += cb[      2*c];   s1b += cb[      2*c+1];
            s2a += cb[ 64 + 2*c];   s2b += cb[ 64 + 2*c+1];
            mxa = fmaxf(mxa, cb[128 + 2*c]); mxb = fmaxf(mxb, cb[128 + 2*c+1]);
            mna = fminf(mna, cb[192 + 2*c]); mnb = fminf(mnb, cb[192 + 2*c+1]);
        }
        if (end > hi){                            // spill partial to carry[pass]
            float* cb = carry + (size_t)pass*256;
            cb[      2*c] = s1a;  cb[      2*c+1] = s1b;
            cb[ 64 + 2*c] = s2a;  cb[ 64 + 2*c+1] = s2b;
            cb[128 + 2*c] = mxa;  cb[128 + 2*c+1] = mxb;
            cb[192 + 2*c] = mna;  cb[192 + 2*c+1] = mnb;
        } else {                                  // finalize
            float D = (float)d;
            float meana = s1a/D, meanb = s1b/D;
            float sda = sqrtf(fmaxf(s2a/D - meana*meana, 0.f) + EPSV);
            float sdb = sqrtf(fmaxf(s2b/D - meanb*meanb, 0.f) + EPSV);
            unsigned* ag = (unsigned*)(agg + (size_t)node*256) + c;  // packed col pair
            ag[ 0] = pk(meana, meanb);
            ag[32] = pk(mxa,  mxb);
            ag[64] = pk(mna,  mnb);
            ag[96] = pk(sda,  sdb);
            if (c == 0){
                float logd = logf(D + 1.f);
                ab[node*2]   = logd / AVG_D;
                ab[node*2+1] = AVG_D / logd;
            }
        }
    }
}

// ========== post GEMM via MFMA: out = [h|agg]@Wm + a*(agg@W2) + b*(agg@W3) ==========
__global__ __launch_bounds__(256) void k_post(
    const unsigned short* __restrict__ hb, const unsigned short* __restrict__ agg,
    const unsigned short* __restrict__ wfrag2,
    const float* __restrict__ ab, const float* __restrict__ snorm,
    const float* __restrict__ b_post,
    float* __restrict__ out_pre, float* __restrict__ bn_acc)
{
    int tid = threadIdx.x;
    int cg = tid>>6;
    int l = tid&63, lr = l&15, lg = l>>4;
    int col = cg*16 + lr;

    const short8* wf = (const short8*)wfrag2;
    short8 Bm[10], B2[8], B3[8];
    #pragma unroll
    for (int ks=0; ks<10; ks++) Bm[ks] = wf[(ks*4      + cg)*64 + l];
    #pragma unroll
    for (int ks=0; ks<8; ks++){
        B2[ks] = wf[((10+ks)*4 + cg)*64 + l];
        B3[ks] = wf[((18+ks)*4 + cg)*64 + l];
    }
    float bias = b_post[col];
    float bs = 0.f, bq = 0.f;

    for (int t = blockIdx.x; t < NT_POST; t += gridDim.x){
        int nodeA = t*16 + lr;                    // A row = lane&15
        f32x4 aM = {0.f,0.f,0.f,0.f}, a2 = {0.f,0.f,0.f,0.f}, a3 = {0.f,0.f,0.f,0.f};
        #pragma unroll
        for (int ks=0; ks<2; ks++){               // h part: direct bf16 load
            short8 A = *(const short8*)(hb + (size_t)nodeA*64 + ks*32 + lg*8);
            aM = __builtin_amdgcn_mfma_f32_16x16x32_bf16(A, Bm[ks], aM, 0,0,0);
        }
        #pragma unroll
        for (int ks=0; ks<8; ks++){               // agg part
            short8 A = *(const short8*)(agg + (size_t)nodeA*256 + ks*32 + lg*8);
            aM = __builtin_amdgcn_mfma_f32_16x16x32_bf16(A, Bm[2+ks], aM, 0,0,0);
            a2 = __builtin_amdgcn_mfma_f32_16x16x32_bf16(A, B2[ks],  a2, 0,0,0);
            a3 = __builtin_amdgcn_mfma_f32_16x16x32_bf16(A, B3[ks],  a3, 0,0,0);
        }
        #pragma unroll
        for (int r=0; r<4; r++){
            int node = t*16 + lg*4 + r;           // D row = 4*lg + r
            float av = ab[node*2], bv = ab[node*2+1];
            float v = (aM[r] + av*a2[r] + bv*a3[r] + bias) * snorm[node];
            out_pre[(size_t)node*64 + col] = v;
            bs += v; bq = fmaf(v,v,bq);
        }
    }
    bs += __shfl_xor(bs, 16); bs += __shfl_xor(bs, 32);
    bq += __shfl_xor(bq, 16); bq += __shfl_xor(bq, 32);
    if (l < 16){
        atomicAdd(&bn_acc[cg*16 + l], bs);
        atomicAdd(&bn_acc[64 + cg*16 + l], bq);
    }
}

// ========== BatchNorm finalize + apply ==========
__global__ void k_bnfin(const float* __restrict__ bn_acc, const float* __restrict__ gamma,
                        const float* __restrict__ beta, float* __restrict__ bn_fin){
    int c = threadIdx.x;
    float invN = 1.f/(float)N_NODES;
    float mu = bn_acc[c]*invN;
    float ms = bn_acc[64+c]*invN;
    float var = fmaxf(ms - mu*mu, 0.f);
    float scale = gamma[c] / sqrtf(var + 1e-5f);
    bn_fin[c] = scale;
    bn_fin[64+c] = beta[c] - mu*scale;
}
__global__ void k_apply(const float* __restrict__ out_pre, const float* __restrict__ bn_fin,
                        float* __restrict__ out){
    int i = blockIdx.x*256 + threadIdx.x;     // float4 index; 6250*256*4 == N*64
    int c4 = (i & 15) * 4;
    float4 v  = ((const float4*)out_pre)[i];
    float4 sc = *(const float4*)&bn_fin[c4];
    float4 sh = *(const float4*)&bn_fin[64 + c4];
    float4 o;
    o.x = fmaf(v.x, sc.x, sh.x); o.y = fmaf(v.y, sc.y, sh.y);
    o.z = fmaf(v.z, sc.z, sh.z); o.w = fmaf(v.w, sc.w, sh.w);
    ((float4*)out)[i] = o;
}

extern "C" void kernel_launch(void* const* d_in, const int* in_sizes, int n_in,
                              void* d_out, int out_size, void* d_ws, size_t ws_size,
                              hipStream_t stream)
{
    const float* h      = (const float*)d_in[0];
    const float* e_in   = (const float*)d_in[1];
    const float* snorm  = (const float*)d_in[2];
    const float* W_pre  = (const float*)d_in[3];
    const float* b_pre  = (const float*)d_in[4];
    const float* W_post = (const float*)d_in[5];
    const float* b_post = (const float*)d_in[6];
    const float* gamma  = (const float*)d_in[7];
    const float* beta   = (const float*)d_in[8];
    const int*   src    = (const int*)d_in[9];
    const int*   dst    = (const int*)d_in[10];

    char* ws = (char*)d_ws;
    unsigned* deg      = (unsigned*)(ws + OFF_DEG);
    unsigned* rowlocal = (unsigned*)(ws + OFF_ROWLOCAL);
    unsigned* bsum     = (unsigned*)(ws + OFF_BSUM);
    unsigned* boffs    = (unsigned*)(ws + OFF_BOFFS);
    unsigned* rowstart = (unsigned*)(ws + OFF_ROWSTART);
    unsigned* cursor   = (unsigned*)(ws + OFF_CURSOR);
    ERec*     erec     = (ERec*)(ws + OFF_EREC);
    float*    abuf     = (float*)(ws + OFF_AB);
    float*    bnacc    = (float*)(ws + OFF_BNACC);
    float*    bnfin    = (float*)(ws + OFF_BNFIN);
    unsigned short* hb     = (unsigned short*)(ws + OFF_HB);
    unsigned short* mbuf   = (unsigned short*)(ws + OFF_MBUF);
    unsigned short* aggp   = (unsigned short*)(ws + OFF_AGG);
    unsigned short* wfrag  = (unsigned short*)(ws + OFF_WFRAG);
    unsigned short* wfrag2 = (unsigned short*)(ws + OFF_WFRAG2);
    float*    carry    = (float*)(ws + OFF_CARRY);
    float*    outpre   = (float*)(ws + OFF_OUTPRE);

    hipMemsetAsync(ws + OFF_DEG,    0, 400000, stream);
    hipMemsetAsync(ws + OFF_CURSOR, 0, 400000, stream);
    hipMemsetAsync(ws + OFF_BNACC,  0, 512,    stream);

    k_prep   <<<4688, 256, 0, stream>>>(dst, deg, h, hb, W_pre, wfrag, W_post, wfrag2);
    k_scan1  <<<391,  256, 0, stream>>>(deg, rowlocal, bsum);
    k_scan2  <<<1,    512, 0, stream>>>(bsum, boffs);
    k_scan3  <<<391,  256, 0, stream>>>(rowlocal, boffs, rowstart);
    k_scatter<<<4688, 256, 0, stream>>>(src, dst, rowstart, cursor, erec);

    for (int pass = 0; pass < NPASS; pass++){
        k_edge <<<6250, 256, 0, stream>>>(hb, e_in, wfrag, b_pre, erec, mbuf, pass);
        k_agg  <<<25000,256, 0, stream>>>(mbuf, rowstart, deg, aggp, abuf, carry, pass);
    }

    k_post   <<<1024, 256, 0, stream>>>(hb, aggp, wfrag2, abuf, snorm, b_post, outpre, bnacc);
    k_bnfin  <<<1,    64,  0, stream>>>(bnacc, gamma, beta, bnfin);
    k_apply  <<<6250, 256, 0, stream>>>(outpre, bnfin, (float*)d_out);
}

// Round 9
// 479.494 us; speedup vs baseline: 1.5255x; 1.1174x over previous
//
#include <hip/hip_runtime.h>
#include <hip/hip_bf16.h>
#include <math.h>

#define N_NODES 100000
#define N_EDGES 1200000
#define NT_EDGE 75000          // total 16-edge tiles
#define NPASS   3
#define TILES_PER_PASS 25000   // NT_EDGE / NPASS
#define ROWS_PER_PASS  400000  // TILES_PER_PASS * 16
#define NT_POST 6250           // node tiles of 16
#define AVG_D   2.5649493574615367f
#define EPSV    1e-5f

#define BUK_SHIFT 9
#define NBUK 196               // ceil(N_NODES/512)
#define EB_PER_BLOCK 4096      // k_bin edges per block (16/thread)

typedef __attribute__((ext_vector_type(8))) short short8;
typedef __attribute__((ext_vector_type(4))) float f32x4;

struct ERec { unsigned eid, sn, dn; };   // 12 B packed CSR record

// ---- workspace layout (bytes), total 132,132,096 (< 135,205,120 proven) ----
#define OFF_DEG       0u
#define OFF_ROWLOCAL  400000u
#define OFF_BSUM      800000u         // 2048; dead after scans -> reused as CARRY
#define OFF_BOFFS     802048u
#define OFF_ROWSTART  804096u
#define OFF_CURSOR    1204096u        // now: bucket cursors (196 u32)
#define OFF_EREC      1604096u        // E * 12 B = 14.4 MB
#define OFF_AB        16004096u       // N*2 f32
#define OFF_BNACC     16804096u       // 128 f32
#define OFF_BNFIN     16804608u       // 128 f32
#define OFF_HB        16805120u       // N*64 bf16 = 12.8 MB
#define OFF_MBUF      29605120u       // 400000 rows * 64 bf16 = 51.2 MB
#define OFF_AGG       80805120u       // N*256 bf16 = 51.2 MB
#define OFF_WFRAG     132005120u      // 5*4*64*8 bf16 = 20,480 B  (k_edge B-frags)
#define OFF_WFRAG2    132025600u      // 26*4*64*8 bf16 = 106,496 B (k_post B-frags)
#define OFF_CARRY     OFF_BSUM        // 2 splits * 4 stats * 64 f32 = 2048 B
#define OFF_STAGING   OFF_MBUF        // E*12 B staging, dead before first k_edge
#define OFF_OUTPRE    OFF_MBUF        // N*64 f32, mbuf dead by k_post

__device__ __forceinline__ short f2b(float f){          // fp32 -> bf16 bits (RNE)
    union { float f; unsigned u; } c; c.f = f;
    unsigned u = c.u;
    unsigned r = (u + 0x7fffu + ((u >> 16) & 1u)) >> 16;
    return (short)r;
}
__device__ __forceinline__ float b2f(unsigned u16){     // bf16 bits (low 16) -> fp32
    union { unsigned u; float f; } c; c.u = u16 << 16;
    return c.f;
}
__device__ __forceinline__ unsigned pk(float a, float b){
    return ((unsigned)(unsigned short)f2b(a)) | (((unsigned)(unsigned short)f2b(b)) << 16);
}

// ========== CSR build + h->bf16 + weight-fragment precompute ==========
__global__ void k_prep(const int* __restrict__ dst, unsigned* __restrict__ deg,
                       const float* __restrict__ h, unsigned short* __restrict__ hb,
                       const float* __restrict__ W_pre, unsigned short* __restrict__ wfrag,
                       const float* __restrict__ W_post, unsigned short* __restrict__ wfrag2){
    int i = blockIdx.x*256 + threadIdx.x;
    if (i < N_EDGES) atomicAdd(&deg[dst[i]], 1u);
    if (i < 800000){                                    // 8 floats per thread
        const float4* p = (const float4*)h + (size_t)i*2;
        float4 u0 = p[0], u1 = p[1];
        uint4 o;
        o.x = pk(u0.x,u0.y); o.y = pk(u0.z,u0.w);
        o.z = pk(u1.x,u1.y); o.w = pk(u1.z,u1.w);
        ((uint4*)hb)[i] = o;
    }
    // W_pre fragments: layout ((ks*4+cg)*64 + lane)*8 + e ; K padded 144->160
    if (i < 10240){
        int e = i & 7, l = (i>>3) & 63, q = i>>9;       // q = ks*4+cg
        int ks = q>>2, cg = q&3;
        int lr = l&15, lg = l>>4;
        int k = ks*32 + lg*8 + e, col = cg*16 + lr;
        wfrag[i] = (unsigned short)((k < 144) ? f2b(W_pre[k*64 + col]) : (short)0);
    }
    // W_post fragments: layout ((f*4+cg)*64 + lane)*8 + e ; f<10:Bm, 10..17:B2, 18..25:B3
    if (i < 53248){
        int e = i & 7, l = (i>>3) & 63, g = i>>9;       // g = f*4+cg
        int cg = g & 3, f = g>>2;
        int lr = l&15, lg = l>>4;
        int col = cg*16 + lr;
        int row;
        if      (f < 10) row = f*32        + lg*8 + e;
        else if (f < 18) row = 320 + (f-10)*32 + lg*8 + e;
        else             row = 576 + (f-18)*32 + lg*8 + e;
        wfrag2[i] = (unsigned short)f2b(W_post[row*64 + col]);
    }
}
__global__ void k_scan1(const unsigned* __restrict__ deg, unsigned* __restrict__ rowlocal,
                        unsigned* __restrict__ bsum){
    __shared__ unsigned s[256];
    int t = threadIdx.x; int i = blockIdx.x*256 + t;
    unsigned d = (i < N_NODES) ? deg[i] : 0u;
    s[t] = d; __syncthreads();
    for (int off=1; off<256; off<<=1){
        unsigned v = (t>=off) ? s[t-off] : 0u; __syncthreads();
        s[t] += v; __syncthreads();
    }
    if (i < N_NODES) rowlocal[i] = s[t] - d;
    if (t == 255) bsum[blockIdx.x] = s[255];
}
__global__ void k_scan2(const unsigned* __restrict__ bsum, unsigned* __restrict__ boffs){
    __shared__ unsigned s[512];
    int t = threadIdx.x;
    unsigned v = (t < 391) ? bsum[t] : 0u;
    s[t] = v; __syncthreads();
    for (int off=1; off<512; off<<=1){
        unsigned x = (t>=off) ? s[t-off] : 0u; __syncthreads();
        s[t] += x; __syncthreads();
    }
    boffs[t] = s[t] - v;
}
__global__ void k_scan3(const unsigned* __restrict__ rowlocal, const unsigned* __restrict__ boffs,
                        unsigned* __restrict__ rowstart, unsigned* __restrict__ bukCursor){
    int i = blockIdx.x*256 + threadIdx.x;
    if (i < N_NODES){
        unsigned v = rowlocal[i] + boffs[i>>8];
        rowstart[i] = v;
        if ((i & 511) == 0) bukCursor[i>>BUK_SHIFT] = v;   // bucket staging base
    }
}

// ========== phase B: bin edges by dst-bucket into staging (chunk-reserved, L2-merging) ====
__global__ __launch_bounds__(256) void k_bin(
    const int* __restrict__ src, const int* __restrict__ dst,
    unsigned* __restrict__ bukCursor, ERec* __restrict__ staging)
{
    __shared__ unsigned hist[NBUK];
    __shared__ unsigned gbase[NBUK];
    int tid = threadIdx.x;
    for (int j=tid; j<NBUK; j+=256) hist[j]=0u;
    __syncthreads();
    int base = blockIdx.x*EB_PER_BLOCK;                // grid 293 -> covers E
    int sn[16], dn[16];
    #pragma unroll
    for (int k=0;k<16;k++){
        int i = base + k*256 + tid;                    // coalesced
        if (i < N_EDGES){
            sn[k]=src[i]; dn[k]=dst[i];
            atomicAdd(&hist[dn[k]>>BUK_SHIFT],1u);
        } else dn[k] = -1;
    }
    __syncthreads();
    for (int j=tid; j<NBUK; j+=256){
        unsigned c = hist[j];
        gbase[j] = c ? atomicAdd(&bukCursor[j], c) : 0u;
        hist[j] = 0u;                                  // reuse as local cursor
    }
    __syncthreads();
    #pragma unroll
    for (int k=0;k<16;k++){
        int i = base + k*256 + tid;
        if (i < N_EDGES){
            int b = dn[k]>>BUK_SHIFT;
            unsigned off = atomicAdd(&hist[b],1u);
            ERec r; r.eid=(unsigned)i; r.sn=(unsigned)sn[k]; r.dn=(unsigned)dn[k];
            staging[gbase[b]+off] = r;
        }
    }
}

// ========== phase C: per-bucket placement into CSR order (LDS cursors, L2-local writes) ===
__global__ __launch_bounds__(256) void k_place(
    const ERec* __restrict__ staging, const unsigned* __restrict__ rowstart,
    ERec* __restrict__ erec)
{
    __shared__ unsigned cur[512];
    int b = blockIdx.x;                                // grid == NBUK, bucket-exclusive
    int nbase = b<<BUK_SHIFT;
    int nend  = nbase + 512; if (nend > N_NODES) nend = N_NODES;
    int tid = threadIdx.x;
    for (int j=tid; j<512; j+=256)
        cur[j] = (nbase+j < N_NODES) ? rowstart[nbase+j] : (unsigned)N_EDGES;
    __syncthreads();
    unsigned p0 = rowstart[nbase];
    unsigned p1 = (nend < N_NODES) ? rowstart[nend] : (unsigned)N_EDGES;
    for (unsigned p = p0 + tid; p < p1; p += 256){
        ERec r = staging[p];
        unsigned pos = atomicAdd(&cur[r.dn - nbase], 1u);
        erec[pos] = r;
    }
}

// ========== edge GEMM via MFMA: 1 tile/wave, B-frags via LDS ==========
__global__ __launch_bounds__(256) void k_edge(
    const unsigned short* __restrict__ hb, const float* __restrict__ e_in,
    const unsigned short* __restrict__ wfrag, const float* __restrict__ b_pre,
    const ERec* __restrict__ erec, unsigned short* __restrict__ mbuf, int pass)
{
    __shared__ __align__(16) uint4 wfl[1280];            // 20,480 B = 20 frag-groups
    int tid = threadIdx.x;
    int wv = tid>>6, l = tid&63;
    int lr = l&15, lg = l>>4;

    int t = blockIdx.x*4 + wv;                           // grid 6250*4 == TILES_PER_PASS
    const ERec* er = erec + (size_t)pass*ROWS_PER_PASS;
    ERec r = er[(size_t)t*16 + lr];                      // issue gather chain head early

    for (int j=tid; j<1280; j+=256) wfl[j] = ((const uint4*)wfrag)[j];
    __syncthreads();

    const unsigned short* ps = hb + (size_t)r.sn*64 + lg*8;
    const unsigned short* pd = hb + (size_t)r.dn*64 + lg*8;
    short8 A[5];
    A[0] = *(const short8*)ps;                           // h[src] cols 0..31
    A[1] = *(const short8*)(ps + 32);                    // h[src] cols 32..63
    A[2] = *(const short8*)pd;                           // h[dst] cols 0..31
    A[3] = *(const short8*)(pd + 32);                    // h[dst] cols 32..63
    {
        short8 A4 = {0,0,0,0,0,0,0,0};
        if (lg < 2){
            const float* pe = e_in + (size_t)r.eid*16 + lg*8;
            float4 u0 = *(const float4*)pe, u1 = *(const float4*)(pe+4);
            A4[0]=f2b(u0.x); A4[1]=f2b(u0.y); A4[2]=f2b(u0.z); A4[3]=f2b(u0.w);
            A4[4]=f2b(u1.x); A4[5]=f2b(u1.y); A4[6]=f2b(u1.z); A4[7]=f2b(u1.w);
        }
        A[4] = A4;
    }

    f32x4 acc[4];
    #pragma unroll
    for (int cg=0; cg<4; cg++) acc[cg] = (f32x4){0.f,0.f,0.f,0.f};
    #pragma unroll
    for (int ks=0; ks<5; ks++){
        #pragma unroll
        for (int cg=0; cg<4; cg++){
            short8 b = ((const short8*)wfl)[(ks*4+cg)*64 + l];   // ds_read_b128
            acc[cg] = __builtin_amdgcn_mfma_f32_16x16x32_bf16(A[ks], b, acc[cg], 0,0,0);
        }
    }
    float bias[4];
    #pragma unroll
    for (int cg=0; cg<4; cg++) bias[cg] = b_pre[cg*16 + lr];
    #pragma unroll
    for (int rr=0; rr<4; rr++){
        size_t row = (size_t)t*16 + lg*4 + rr;
        #pragma unroll
        for (int cg=0; cg<4; cg++)
            mbuf[row*64 + cg*16 + lr] = (unsigned short)f2b(acc[cg][rr] + bias[cg]);
    }
}

// ========== segment aggregation over CSR rows (pass-windowed, carry at splits) ==========
__global__ __launch_bounds__(256) void k_agg(
    const unsigned short* __restrict__ mbuf, const unsigned* __restrict__ rowstart,
    const unsigned* __restrict__ deg, unsigned short* __restrict__ agg,
    float* __restrict__ ab, float* __restrict__ carry, int pass)
{
    int wv = threadIdx.x>>6, l = threadIdx.x&63;
    int node = blockIdx.x*4 + wv;                 // grid 25000*4 == N
    int hf = l>>5, c = l&31;                      // lane c handles cols 2c, 2c+1
    unsigned start = rowstart[node];
    int d = (int)deg[node];                       // d >= 1 (dst includes arange(N))
    unsigned end = start + (unsigned)d;
    unsigned lo = (unsigned)pass * ROWS_PER_PASS;
    unsigned hi = lo + ROWS_PER_PASS;
    if (end <= lo || start >= hi) return;
    unsigned a = start < lo ? lo : start;
    unsigned b = end > hi ? hi : end;
    int n = (int)(b - a);
    const unsigned short* p = mbuf + (size_t)(a - lo)*64 + 2*c;
    float s1a=0.f,s2a=0.f,mxa=-3.402823466e38f,mna=3.402823466e38f;
    float s1b=0.f,s2b=0.f,mxb=-3.402823466e38f,mnb=3.402823466e38f;
    for (int i=hf; i<n; i+=2){                    // 2 rows in flight, 256 B/wave-iter
        unsigned v = *(const unsigned*)(p + (size_t)i*64);
        float va = b2f(v & 0xffffu), vb = b2f(v >> 16);
        s1a += va; s2a = fmaf(va,va,s2a); mxa = fmaxf(mxa,va); mna = fminf(mna,va);
        s1b += vb; s2b = fmaf(vb,vb,s2b); mxb = fmaxf(mxb,vb); mnb = fminf(mnb,vb);
    }
    s1a += __shfl_xor(s1a,32); s2a += __shfl_xor(s2a,32);
    mxa = fmaxf(mxa,__shfl_xor(mxa,32)); mna = fminf(mna,__shfl_xor(mna,32));
    s1b += __shfl_xor(s1b,32); s2b += __shfl_xor(s2b,32);
    mxb = fmaxf(mxb,__shfl_xor(mxb,32)); mnb = fminf(mnb,__shfl_xor(mnb,32));
    if (l < 32){
        if (start < lo){                          // merge carry from split (pass-1)
            const float* cb = carry + (size_t)(pass-1)*256;
            s1a += cb[      2*c];   s1b += cb[      2*c+1];
            s2a += cb[ 64 + 2*c];   s2b += cb[ 64 + 2*c+1];
            mxa = fmaxf(mxa, cb[128 + 2*c]); mxb = fmaxf(mxb, cb[128 + 2*c+1]);
            mna = fminf(mna, cb[192 + 2*c]); mnb = fminf(mnb, cb[192 + 2*c+1]);
        }
        if (end > hi){                            // spill partial to carry[pass]
            float* cb = carry + (size_t)pass*256;
            cb[      2*c] = s1a;  cb[      2*c+1] = s1b;
            cb[ 64 + 2*c] = s2a;  cb[ 64 + 2*c+1] = s2b;
            cb[128 + 2*c] = mxa;  cb[128 + 2*c+1] = mxb;
            cb[192 + 2*c] = mna;  cb[192 + 2*c+1] = mnb;
        } else {                                  // finalize
            float D = (float)d;
            float meana = s1a/D, meanb = s1b/D;
            float sda = sqrtf(fmaxf(s2a/D - meana*meana, 0.f) + EPSV);
            float sdb = sqrtf(fmaxf(s2b/D - meanb*meanb, 0.f) + EPSV);
            unsigned* ag = (unsigned*)(agg + (size_t)node*256) + c;  // packed col pair
            ag[ 0] = pk(meana, meanb);
            ag[32] = pk(mxa,  mxb);
            ag[64] = pk(mna,  mnb);
            ag[96] = pk(sda,  sdb);
            if (c == 0){
                float logd = logf(D + 1.f);
                ab[node*2]   = logd / AVG_D;
                ab[node*2+1] = AVG_D / logd;
            }
        }
    }
}

// ========== post GEMM via MFMA: out = [h|agg]@Wm + a*(agg@W2) + b*(agg@W3) ==========
__global__ __launch_bounds__(256) void k_post(
    const unsigned short* __restrict__ hb, const unsigned short* __restrict__ agg,
    const unsigned short* __restrict__ wfrag2,
    const float* __restrict__ ab, const float* __restrict__ snorm,
    const float* __restrict__ b_post,
    float* __restrict__ out_pre, float* __restrict__ bn_acc)
{
    int tid = threadIdx.x;
    int cg = tid>>6;
    int l = tid&63, lr = l&15, lg = l>>4;
    int col = cg*16 + lr;

    const short8* wf = (const short8*)wfrag2;
    short8 Bm[10], B2[8], B3[8];
    #pragma unroll
    for (int ks=0; ks<10; ks++) Bm[ks] = wf[(ks*4      + cg)*64 + l];
    #pragma unroll
    for (int ks=0; ks<8; ks++){
        B2[ks] = wf[((10+ks)*4 + cg)*64 + l];
        B3[ks] = wf[((18+ks)*4 + cg)*64 + l];
    }
    float bias = b_post[col];
    float bs = 0.f, bq = 0.f;

    for (int t = blockIdx.x; t < NT_POST; t += gridDim.x){
        int nodeA = t*16 + lr;                    // A row = lane&15
        f32x4 aM = {0.f,0.f,0.f,0.f}, a2 = {0.f,0.f,0.f,0.f}, a3 = {0.f,0.f,0.f,0.f};
        #pragma unroll
        for (int ks=0; ks<2; ks++){               // h part: direct bf16 load
            short8 A = *(const short8*)(hb + (size_t)nodeA*64 + ks*32 + lg*8);
            aM = __builtin_amdgcn_mfma_f32_16x16x32_bf16(A, Bm[ks], aM, 0,0,0);
        }
        #pragma unroll
        for (int ks=0; ks<8; ks++){               // agg part
            short8 A = *(const short8*)(agg + (size_t)nodeA*256 + ks*32 + lg*8);
            aM = __builtin_amdgcn_mfma_f32_16x16x32_bf16(A, Bm[2+ks], aM, 0,0,0);
            a2 = __builtin_amdgcn_mfma_f32_16x16x32_bf16(A, B2[ks],  a2, 0,0,0);
            a3 = __builtin_amdgcn_mfma_f32_16x16x32_bf16(A, B3[ks],  a3, 0,0,0);
        }
        #pragma unroll
        for (int r=0; r<4; r++){
            int node = t*16 + lg*4 + r;           // D row = 4*lg + r
            float av = ab[node*2], bv = ab[node*2+1];
            float v = (aM[r] + av*a2[r] + bv*a3[r] + bias) * snorm[node];
            out_pre[(size_t)node*64 + col] = v;
            bs += v; bq = fmaf(v,v,bq);
        }
    }
    bs += __shfl_xor(bs, 16); bs += __shfl_xor(bs, 32);
    bq += __shfl_xor(bq, 16); bq += __shfl_xor(bq, 32);
    if (l < 16){
        atomicAdd(&bn_acc[cg*16 + l], bs);
        atomicAdd(&bn_acc[64 + cg*16 + l], bq);
    }
}

// ========== BatchNorm finalize + apply ==========
__global__ void k_bnfin(const float* __restrict__ bn_acc, const float* __restrict__ gamma,
                        const float* __restrict__ beta, float* __restrict__ bn_fin){
    int c = threadIdx.x;
    float invN = 1.f/(float)N_NODES;
    float mu = bn_acc[c]*invN;
    float ms = bn_acc[64+c]*invN;
    float var = fmaxf(ms - mu*mu, 0.f);
    float scale = gamma[c] / sqrtf(var + 1e-5f);
    bn_fin[c] = scale;
    bn_fin[64+c] = beta[c] - mu*scale;
}
__global__ void k_apply(const float* __restrict__ out_pre, const float* __restrict__ bn_fin,
                        float* __restrict__ out){
    int i = blockIdx.x*256 + threadIdx.x;     // float4 index; 6250*256*4 == N*64
    int c4 = (i & 15) * 4;
    float4 v  = ((const float4*)out_pre)[i];
    float4 sc = *(const float4*)&bn_fin[c4];
    float4 sh = *(const float4*)&bn_fin[64 + c4];
    float4 o;
    o.x = fmaf(v.x, sc.x, sh.x); o.y = fmaf(v.y, sc.y, sh.y);
    o.z = fmaf(v.z, sc.z, sh.z); o.w = fmaf(v.w, sc.w, sh.w);
    ((float4*)out)[i] = o;
}

extern "C" void kernel_launch(void* const* d_in, const int* in_sizes, int n_in,
                              void* d_out, int out_size, void* d_ws, size_t ws_size,
                              hipStream_t stream)
{
    const float* h      = (const float*)d_in[0];
    const float* e_in   = (const float*)d_in[1];
    const float* snorm  = (const float*)d_in[2];
    const float* W_pre  = (const float*)d_in[3];
    const float* b_pre  = (const float*)d_in[4];
    const float* W_post = (const float*)d_in[5];
    const float* b_post = (const float*)d_in[6];
    const float* gamma  = (const float*)d_in[7];
    const float* beta   = (const float*)d_in[8];
    const int*   src    = (const int*)d_in[9];
    const int*   dst    = (const int*)d_in[10];

    char* ws = (char*)d_ws;
    unsigned* deg      = (unsigned*)(ws + OFF_DEG);
    unsigned* rowlocal = (unsigned*)(ws + OFF_ROWLOCAL);
    unsigned* bsum     = (unsigned*)(ws + OFF_BSUM);
    unsigned* boffs    = (unsigned*)(ws + OFF_BOFFS);
    unsigned* rowstart = (unsigned*)(ws + OFF_ROWSTART);
    unsigned* bukCur   = (unsigned*)(ws + OFF_CURSOR);
    ERec*     erec     = (ERec*)(ws + OFF_EREC);
    ERec*     staging  = (ERec*)(ws + OFF_STAGING);
    float*    abuf     = (float*)(ws + OFF_AB);
    float*    bnacc    = (float*)(ws + OFF_BNACC);
    float*    bnfin    = (float*)(ws + OFF_BNFIN);
    unsigned short* hb     = (unsigned short*)(ws + OFF_HB);
    unsigned short* mbuf   = (unsigned short*)(ws + OFF_MBUF);
    unsigned short* aggp   = (unsigned short*)(ws + OFF_AGG);
    unsigned short* wfrag  = (unsigned short*)(ws + OFF_WFRAG);
    unsigned short* wfrag2 = (unsigned short*)(ws + OFF_WFRAG2);
    float*    carry    = (float*)(ws + OFF_CARRY);
    float*    outpre   = (float*)(ws + OFF_OUTPRE);

    hipMemsetAsync(ws + OFF_DEG,   0, 400000, stream);
    hipMemsetAsync(ws + OFF_BNACC, 0, 512,    stream);

    k_prep   <<<4688, 256, 0, stream>>>(dst, deg, h, hb, W_pre, wfrag, W_post, wfrag2);
    k_scan1  <<<391,  256, 0, stream>>>(deg, rowlocal, bsum);
    k_scan2  <<<1,    512, 0, stream>>>(bsum, boffs);
    k_scan3  <<<391,  256, 0, stream>>>(rowlocal, boffs, rowstart, bukCur);
    k_bin    <<<293,  256, 0, stream>>>(src, dst, bukCur, staging);
    k_place  <<<NBUK, 256, 0, stream>>>(staging, rowstart, erec);

    for (int pass = 0; pass < NPASS; pass++){
        k_edge <<<6250, 256, 0, stream>>>(hb, e_in, wfrag, b_pre, erec, mbuf, pass);
        k_agg  <<<25000,256, 0, stream>>>(mbuf, rowstart, deg, aggp, abuf, carry, pass);
    }

    k_post   <<<1024, 256, 0, stream>>>(hb, aggp, wfrag2, abuf, snorm, b_post, outpre, bnacc);
    k_bnfin  <<<1,    64,  0, stream>>>(bnacc, gamma, beta, bnfin);
    k_apply  <<<6250, 256, 0, stream>>>(outpre, bnfin, (float*)d_out);
}